// Round 5
// baseline (359.819 us; speedup 1.0000x reference)
//
#include <hip/hip_runtime.h>

#define BATCH   8
#define LENGTH  4096
#define IN_DIM  512
#define STATE   256
#define OUT_DIM 512
#define NC      64
#define LC      64

typedef __attribute__((ext_vector_type(8)))  short bf16x8;
typedef __attribute__((ext_vector_type(16))) float f32x16;

union FragU { bf16x8 v; unsigned u[4]; };

__device__ __forceinline__ unsigned short bf16_rne(float v) {
    unsigned u = __builtin_bit_cast(unsigned, v);
    unsigned r = (u + 0x7FFFu + ((u >> 16) & 1u)) >> 16;
    return (unsigned short)r;
}
__device__ __forceinline__ float bf16_f(unsigned short h) {
    unsigned u = ((unsigned)h) << 16;
    return __builtin_bit_cast(float, u);
}

// ---------------------------------------------------------------------------
// Split + transpose a weight: in[K][Nsrc] fp32 -> hi/lo bf16 [Nsrc][K] (RNE).
// ---------------------------------------------------------------------------
__global__ __launch_bounds__(256) void split_T_kernel(
    const float* __restrict__ in, unsigned short* __restrict__ hi,
    unsigned short* __restrict__ lo, int kbits, int Nsrc)
{
    int id = blockIdx.x * 256 + threadIdx.x;
    int k = id & ((1 << kbits) - 1);
    int n = id >> kbits;
    float v = in[(size_t)k * Nsrc + n];
    unsigned short h = bf16_rne(v);
    hi[id] = h;
    lo[id] = bf16_rne(v - bf16_f(h));
}

// ---------------------------------------------------------------------------
// Split-bf16 MFMA GEMM. Same tiling/layouts/epilogue as round 4 (validated):
// 256 thr = 4 waves, wave-tile 64x64 (2x2 of 32x32x16), block tile 128x128,
// BK=32, A fp32 split in-register, acc += Ahi*Bhi + Alo*Bhi + Ahi*Blo.
//
// ONE change vs round 4: staging is buffer_load -> VGPR ping-pong ->
// ds_write_b128 (the AITER/hipBLASLt path) instead of global_load_lds.
// Evidence: rounds 2/3/4 all staged 256 MB/GEMM via global_load_lds and all
// pinned at ~46 us (= ~9 B/cyc/CU through the LDS-DMA engine) regardless of
// structure. Global reads here are plainly coalesced (swizzle applied on the
// ds_write side, where per-lane scatter is legal).
//
// LDS (single 32KB buffer): A fp32 [0,16K): row*128B, 8 slots, phys=l^(row&7)
//                           Bhi [16K,24K), Blo [24K,32K): row*64B, 4 slots,
//                           phys = l ^ ((row>>1)&3)
// ---------------------------------------------------------------------------
template<int K>
__global__ __launch_bounds__(256, 2) void gemm_stage(
    const float* __restrict__ Af, const unsigned short* __restrict__ Bthi,
    const unsigned short* __restrict__ Btlo, float* __restrict__ Cc, int N_)
{
    __shared__ unsigned short lds[16384];   // 32 KB

    const int tid  = threadIdx.x;
    const int wave = tid >> 6;
    const int lane = tid & 63;
    const int n0 = blockIdx.x * 128;
    const int m0 = blockIdx.y * 128;

    // --- per-thread staging descriptors: 8 chunks of 16B each -------------
    const char* gp[8];
    int ldsb[8], gstep[8];
    #pragma unroll
    for (int i = 0; i < 8; ++i) {
        int c = i * 256 + tid;
        if (c < 1024) {                       // A plane: 1024 chunks (16 KB)
            int row = c >> 3, sub = c & 7;
            gp[i] = (const char*)(Af + (size_t)(m0 + row) * K) + sub * 16;
            gstep[i] = 32 * 4;                // BK fp32 = 128 B
            ldsb[i] = row * 128 + ((sub ^ (row & 7)) * 16);
        } else {                              // B planes: 512 chunks each
            int d = c - 1024;
            int pl = d >> 9;                  // 0 = hi, 1 = lo
            int e = d & 511;
            int row = e >> 2, sub = e & 3;
            const unsigned short* bsrc = pl ? Btlo : Bthi;
            gp[i] = (const char*)(bsrc + (size_t)(n0 + row) * K) + sub * 16;
            gstep[i] = 32 * 2;                // BK bf16 = 64 B
            ldsb[i] = 16384 + pl * 8192 + row * 64 + ((sub ^ ((row >> 1) & 3)) * 16);
        }
    }

    const int l31 = lane & 31, q2 = lane >> 5;
    const int wm = (wave >> 1) * 64, wn = (wave & 1) * 64;

    // fragment read offsets (ushort units) — identical to round 4
    int aoff[2][2][2];
    #pragma unroll
    for (int mi = 0; mi < 2; ++mi) {
        int row = wm + mi * 32 + l31;
        #pragma unroll
        for (int ks = 0; ks < 2; ++ks)
            #pragma unroll
            for (int h = 0; h < 2; ++h)
                aoff[mi][ks][h] = row * 64 + ((ks * 4 + q2 * 2 + h) ^ (row & 7)) * 8;
    }
    int boff[2][2];
    #pragma unroll
    for (int nj = 0; nj < 2; ++nj) {
        int row = wn + nj * 32 + l31;
        #pragma unroll
        for (int ks = 0; ks < 2; ++ks)
            boff[nj][ks] = row * 32 + (((ks * 2 + q2) ^ ((row >> 1) & 3))) * 8;
    }

    f32x16 acc[2][2];
    #pragma unroll
    for (int mi = 0; mi < 2; ++mi)
        #pragma unroll
        for (int nj = 0; nj < 2; ++nj)
            #pragma unroll
            for (int r = 0; r < 16; ++r) acc[mi][nj][r] = 0.f;

    auto load_tile = [&](float4* s) {
        #pragma unroll
        for (int i = 0; i < 8; ++i) {
            s[i] = *(const float4*)(gp[i]);
            gp[i] += gstep[i];
        }
    };
    auto store_tile = [&](const float4* s) {
        #pragma unroll
        for (int i = 0; i < 8; ++i)
            *(float4*)((char*)lds + ldsb[i]) = s[i];
    };
    auto compute = [&]() {
        #pragma unroll
        for (int ks = 0; ks < 2; ++ks) {
            FragU ahi[2], alo[2];
            #pragma unroll
            for (int mi = 0; mi < 2; ++mi) {
                float4 f0 = *(const float4*)(lds + aoff[mi][ks][0]);
                float4 f1 = *(const float4*)(lds + aoff[mi][ks][1]);
                unsigned b0 = __builtin_bit_cast(unsigned, f0.x);
                unsigned b1 = __builtin_bit_cast(unsigned, f0.y);
                unsigned b2 = __builtin_bit_cast(unsigned, f0.z);
                unsigned b3 = __builtin_bit_cast(unsigned, f0.w);
                unsigned b4 = __builtin_bit_cast(unsigned, f1.x);
                unsigned b5 = __builtin_bit_cast(unsigned, f1.y);
                unsigned b6 = __builtin_bit_cast(unsigned, f1.z);
                unsigned b7 = __builtin_bit_cast(unsigned, f1.w);
                ahi[mi].u[0] = __builtin_amdgcn_perm(b1, b0, 0x07060302);
                ahi[mi].u[1] = __builtin_amdgcn_perm(b3, b2, 0x07060302);
                ahi[mi].u[2] = __builtin_amdgcn_perm(b5, b4, 0x07060302);
                ahi[mi].u[3] = __builtin_amdgcn_perm(b7, b6, 0x07060302);
                float l0 = f0.x - __builtin_bit_cast(float, b0 & 0xFFFF0000u);
                float l1 = f0.y - __builtin_bit_cast(float, b1 & 0xFFFF0000u);
                float l2 = f0.z - __builtin_bit_cast(float, b2 & 0xFFFF0000u);
                float l3 = f0.w - __builtin_bit_cast(float, b3 & 0xFFFF0000u);
                float l4 = f1.x - __builtin_bit_cast(float, b4 & 0xFFFF0000u);
                float l5 = f1.y - __builtin_bit_cast(float, b5 & 0xFFFF0000u);
                float l6 = f1.z - __builtin_bit_cast(float, b6 & 0xFFFF0000u);
                float l7 = f1.w - __builtin_bit_cast(float, b7 & 0xFFFF0000u);
                alo[mi].u[0] = __builtin_amdgcn_perm(
                    __builtin_bit_cast(unsigned, l1), __builtin_bit_cast(unsigned, l0), 0x07060302);
                alo[mi].u[1] = __builtin_amdgcn_perm(
                    __builtin_bit_cast(unsigned, l3), __builtin_bit_cast(unsigned, l2), 0x07060302);
                alo[mi].u[2] = __builtin_amdgcn_perm(
                    __builtin_bit_cast(unsigned, l5), __builtin_bit_cast(unsigned, l4), 0x07060302);
                alo[mi].u[3] = __builtin_amdgcn_perm(
                    __builtin_bit_cast(unsigned, l7), __builtin_bit_cast(unsigned, l6), 0x07060302);
            }
            FragU bhi[2], blo[2];
            #pragma unroll
            for (int nj = 0; nj < 2; ++nj) {
                bhi[nj].v = *(const bf16x8*)(lds +  8192 + boff[nj][ks]);
                blo[nj].v = *(const bf16x8*)(lds + 12288 + boff[nj][ks]);
            }
            #pragma unroll
            for (int mi = 0; mi < 2; ++mi)
                #pragma unroll
                for (int nj = 0; nj < 2; ++nj) {
                    acc[mi][nj] = __builtin_amdgcn_mfma_f32_32x32x16_bf16(
                        ahi[mi].v, bhi[nj].v, acc[mi][nj], 0, 0, 0);
                    acc[mi][nj] = __builtin_amdgcn_mfma_f32_32x32x16_bf16(
                        alo[mi].v, bhi[nj].v, acc[mi][nj], 0, 0, 0);
                    acc[mi][nj] = __builtin_amdgcn_mfma_f32_32x32x16_bf16(
                        ahi[mi].v, blo[nj].v, acc[mi][nj], 0, 0, 0);
                }
        }
    };

    // --- pipelined K-loop: regs hold tile t+1 while LDS holds tile t ------
    float4 sA[8], sB[8];
    load_tile(sA);                      // tile 0
    constexpr int nit = K / 32;         // 16 or 8, always even
    #pragma unroll 1
    for (int p = 0; p < nit / 2; ++p) {
        __syncthreads();
        store_tile(sA);                 // tile 2p
        __syncthreads();
        load_tile(sB);                  // tile 2p+1 in flight under compute
        compute();
        __syncthreads();
        store_tile(sB);                 // tile 2p+1
        __syncthreads();
        if (p + 1 < nit / 2) load_tile(sA);   // tile 2p+2
        compute();
    }

    // epilogue: 32x32 C/D layout [m74/m101, round-4-validated]
    #pragma unroll
    for (int mi = 0; mi < 2; ++mi)
        #pragma unroll
        for (int nj = 0; nj < 2; ++nj) {
            #pragma unroll
            for (int r = 0; r < 16; ++r) {
                int row_g = m0 + wm + mi * 32 + 4 * q2 + (r & 3) + 8 * (r >> 2);
                int col_g = n0 + wn + nj * 32 + l31;
                Cc[(size_t)row_g * N_ + col_g] = acc[mi][nj][r];
            }
        }
}

// ---------------------------------------------------------------------------
// Scan phase A: per-chunk carry with zero initial state.
// ---------------------------------------------------------------------------
__global__ __launch_bounds__(256) void scan_carry(
    const float* __restrict__ uB, const float* __restrict__ A,
    float* __restrict__ carry)
{
    const int b = blockIdx.x;
    const int c = blockIdx.y;
    const int n = threadIdx.x;
    const float a = A[n];
    const float* p = uB + ((size_t)b * LENGTH + (size_t)c * LC) * STATE + n;
    float s = 0.f;
    #pragma unroll 8
    for (int j = 0; j < LC; ++j) s = a * s + p[(size_t)j * STATE];
    carry[((size_t)b * NC + c) * STATE + n] = s;
}

// ---------------------------------------------------------------------------
// Scan phase B: tiny sequential combine -> h[b,c] = state entering chunk c.
// (Separate kernel: fusing this into apply created a 63-deep serialized
//  load+FMA chain per block in rounds 3/4.)
// ---------------------------------------------------------------------------
__global__ __launch_bounds__(256) void scan_combine(
    const float* __restrict__ carry, const float* __restrict__ A,
    const float* __restrict__ x0, float* __restrict__ h)
{
    const int b = blockIdx.x;
    const int n = threadIdx.x;
    const float a = A[n];
    float a2 = a * a, a4 = a2 * a2, a8 = a4 * a4, a16 = a8 * a8, a32 = a16 * a16;
    const float aLC = a32 * a32;   // a^64
    float s = x0[(size_t)b * STATE + n];
    for (int c = 0; c < NC; ++c) {
        h[((size_t)b * NC + c) * STATE + n] = s;
        s = aLC * s + carry[((size_t)b * NC + c) * STATE + n];
    }
}

// ---------------------------------------------------------------------------
// Scan phase C: re-apply recurrence from h; write x fp32 + x_last.
// ---------------------------------------------------------------------------
__global__ __launch_bounds__(256) void scan_apply(
    const float* __restrict__ uB, const float* __restrict__ A,
    const float* __restrict__ h, float* __restrict__ x,
    float* __restrict__ x_last)
{
    const int b = blockIdx.x;
    const int c = blockIdx.y;
    const int n = threadIdx.x;
    const float a = A[n];
    float s = h[((size_t)b * NC + c) * STATE + n];
    const size_t base = ((size_t)b * LENGTH + (size_t)c * LC) * STATE + n;
    const float* p = uB + base;
    float* qx = x + base;
    #pragma unroll 8
    for (int j = 0; j < LC; ++j) {
        s = a * s + p[(size_t)j * STATE];
        qx[(size_t)j * STATE] = s;
    }
    if (c == NC - 1) x_last[(size_t)b * STATE + n] = s;
}

// ---------------------------------------------------------------------------
extern "C" void kernel_launch(void* const* d_in, const int* in_sizes, int n_in,
                              void* d_out, int out_size, void* d_ws, size_t ws_size,
                              hipStream_t stream)
{
    const float* u  = (const float*)d_in[0];   // [8,4096,512]
    const float* x0 = (const float*)d_in[1];   // [8,256]
    const float* A  = (const float*)d_in[2];   // [256]
    const float* B  = (const float*)d_in[3];   // [512,256]
    const float* C  = (const float*)d_in[4];   // [256,512]

    const size_t MB = 1024 * 1024;
    char* ws = (char*)d_ws;

    float* x     = (float*)(ws);                               // [M,256] fp32, 32 MB
    float* carry = (float*)(ws + 32 * MB);                     // 512 KB
    float* h     = (float*)(ws + 32 * MB + 512 * 1024);        // 512 KB
    unsigned short* Bt_hi = (unsigned short*)(ws + 33 * MB);                // 256 KB
    unsigned short* Bt_lo = (unsigned short*)(ws + 33 * MB + 256 * 1024);   // 256 KB
    unsigned short* Ct_hi = (unsigned short*)(ws + 33 * MB + 512 * 1024);   // 256 KB
    unsigned short* Ct_lo = (unsigned short*)(ws + 33 * MB + 768 * 1024);   // 256 KB

    float* y      = (float*)d_out;                             // [8,4096,512] = 64 MB
    float* x_last = y + (size_t)BATCH * LENGTH * OUT_DIM;      // [8,256]
    // uB parks in upper half of y's region; dead before GEMM2 writes y.
    float* uB     = (float*)((char*)d_out + 32 * MB);          // [M,256] = 32 MB

    const int M = BATCH * LENGTH;   // 32768

    // 1. split+transpose weights to bf16 hi/lo planes
    split_T_kernel<<<dim3((IN_DIM * STATE) / 256), dim3(256), 0, stream>>>(B, Bt_hi, Bt_lo, 9, STATE);
    split_T_kernel<<<dim3((STATE * OUT_DIM) / 256), dim3(256), 0, stream>>>(C, Ct_hi, Ct_lo, 8, OUT_DIM);

    // 2. GEMM1: uB[M,256] = u[M,512] @ B
    gemm_stage<IN_DIM><<<dim3(STATE / 128, M / 128), dim3(256), 0, stream>>>(
        u, Bt_hi, Bt_lo, uB, STATE);

    // 3. chunked scan (fp32 exact)
    scan_carry  <<<dim3(BATCH, NC), dim3(256), 0, stream>>>(uB, A, carry);
    scan_combine<<<dim3(BATCH),     dim3(256), 0, stream>>>(carry, A, x0, h);
    scan_apply  <<<dim3(BATCH, NC), dim3(256), 0, stream>>>(uB, A, h, x, x_last);

    // 4. GEMM2: y[M,512] = x[M,256] @ C
    gemm_stage<STATE><<<dim3(OUT_DIM / 128, M / 128), dim3(256), 0, stream>>>(
        x, Ct_hi, Ct_lo, y, OUT_DIM);
}